// Round 10
// baseline (445.318 us; speedup 1.0000x reference)
//
#include <hip/hip_runtime.h>
#include <math.h>
#include <stdint.h>

#define N_TOK 4096
#define DIM   1024
#define HID   2048
#define NE    8
#define NROWS (N_TOK * 2)   // 8192 (token, k) assignments
#define LDST  72            // transpose-kernel LDS tile stride (shorts)
#define OBST  128           // ffn1 epilogue bounce stride (shorts)
#define TPT   16            // tokens per thread in scatter_plan (N_TOK/256)
#define CAP1  144           // work ranks per XCD (1152/8) — shared by ffn1 and ffn2

typedef __attribute__((ext_vector_type(8))) short bf16x8;
typedef __attribute__((ext_vector_type(4))) float f32x4;

__device__ __forceinline__ unsigned short f2bf(float f) {
    union { unsigned int i; float f; } v; v.f = f;
    unsigned int u = v.i;
    return (unsigned short)((u + 0x7FFFu + ((u >> 16) & 1u)) >> 16);
}
__device__ __forceinline__ int clampi(int v, int lo, int hi) {
    return v < lo ? lo : (v > hi ? hi : v);
}
__device__ __forceinline__ void cvt8(const float* p, unsigned short* o) {
    float4 a = *(const float4*)p;
    float4 b = *(const float4*)(p + 4);
    o[0] = f2bf(a.x); o[1] = f2bf(a.y); o[2] = f2bf(a.z); o[3] = f2bf(a.w);
    o[4] = f2bf(b.x); o[5] = f2bf(b.y); o[6] = f2bf(b.z); o[7] = f2bf(b.w);
}
__device__ __forceinline__ float fast_gelu(float v) {
    float c = 0.7978845608028654f * (v + 0.044715f * v * v * v);
    float t = 1.f - 2.f / (1.f + __expf(2.f * c));   // tanh(c)
    return 0.5f * v * (1.f + t);
}
// async global->LDS, 16B per lane; LDS dest = wave-uniform base + lane*16 (LINEAR — rule #21)
__device__ __forceinline__ void gload_lds16(const void* g, void* l) {
    __builtin_amdgcn_global_load_lds(
        (const __attribute__((address_space(1))) unsigned int*)g,
        (__attribute__((address_space(3))) unsigned int*)l,
        16, 0, 0);
}

// ---------------- gating: one wave per token, pure fp32, NO ATOMICS ----------------
__global__ __launch_bounds__(256) void gate_kernel(
    const float* __restrict__ x, const float* __restrict__ wg,
    unsigned short* __restrict__ top_e, float* __restrict__ top_g)
{
    int wave = threadIdx.x >> 6;
    int lane = threadIdx.x & 63;
    int n = blockIdx.x * 4 + wave;
    if (n >= N_TOK) return;
    float acc[NE];
#pragma unroll
    for (int e = 0; e < NE; e++) acc[e] = 0.f;
    const float* xrow = x + (size_t)n * DIM;
    for (int d = lane; d < DIM; d += 64) {
        float xv = xrow[d];
        float4 wa = *(const float4*)(wg + (size_t)d * NE);
        float4 wb = *(const float4*)(wg + (size_t)d * NE + 4);
        acc[0] += xv * wa.x; acc[1] += xv * wa.y;
        acc[2] += xv * wa.z; acc[3] += xv * wa.w;
        acc[4] += xv * wb.x; acc[5] += xv * wb.y;
        acc[6] += xv * wb.z; acc[7] += xv * wb.w;
    }
#pragma unroll
    for (int e = 0; e < NE; e++) {
        float v = acc[e];
#pragma unroll
        for (int off = 32; off > 0; off >>= 1) v += __shfl_xor(v, off, 64);
        acc[e] = v;
    }
    if (lane == 0) {
        int e0 = 0; float v0 = acc[0];
#pragma unroll
        for (int e = 1; e < NE; e++) if (acc[e] > v0) { v0 = acc[e]; e0 = e; }
        int e1 = (e0 == 0) ? 1 : 0; float v1 = acc[e1];
#pragma unroll
        for (int e = 0; e < NE; e++) if (e != e0 && acc[e] > v1) { v1 = acc[e]; e1 = e; }
        float s = expf(v1 - v0);
        float g0 = 1.f / (1.f + s);
        float g1 = s / (1.f + s);
        top_e[n] = (unsigned short)(e0 | (e1 << 8));
        top_g[2 * n + 0] = g0;
        top_g[2 * n + 1] = g1;
    }
}

// ---------------- scatter+plan: ONE workgroup, zero atomics, PARALLEL work-list build ----------------
// Work item = (gr0<<16)|(nvalid<<8)|(e<<4)|j, j in [0,16). SHARED by ffn1 (j = nb; two
// nb-half launches) and ffn2 (j = (kh<<3)|nb; two K-half launches). Expert e pinned to
// XCD e; overflow spilled closed-form.
__global__ __launch_bounds__(256) void scatter_plan_kernel(
    const unsigned short* __restrict__ top_e, const float* __restrict__ top_g,
    int* __restrict__ row_tok, float* __restrict__ row_gate,
    int* __restrict__ work1)
{
    __shared__ int lpre[256][NE];   // counts, then exclusive prefix, then running cursor
    __shared__ int etot[NE], ebase[NE];
    __shared__ int Tst[NE + 1];
    __shared__ int kept1[NE], ovb1[NE], fb1[NE + 1];
    int t = threadIdx.x;

    unsigned long long c64 = 0ull;
    unsigned short te[TPT];
#pragma unroll
    for (int i = 0; i < TPT; i++) {
        int v = top_e[t * TPT + i];
        te[i] = (unsigned short)v;
        c64 += 1ull << ((v & 7) * 8);
        c64 += 1ull << (((v >> 8) & 7) * 8);
    }
#pragma unroll
    for (int e = 0; e < NE; e++) lpre[t][e] = (int)((c64 >> (e * 8)) & 0xFF);
    __syncthreads();

    if (t < NE) {                    // one thread per expert: scan 256 entries
        int s = 0;
        for (int i = 0; i < 256; i++) { int c = lpre[i][t]; lpre[i][t] = s; s += c; }
        etot[t] = s;
    }
    __syncthreads();
    if (t == 0) {
        int b = 0, ts = 0;
#pragma unroll
        for (int e = 0; e < NE; e++) {
            ebase[e] = b; b += etot[e];
            Tst[e] = ts; ts += (etot[e] + 127) >> 7;
        }
        Tst[NE] = ts;
        int ob = 0, fs = 0;
#pragma unroll
        for (int e = 0; e < NE; e++) {
            int it = 16 * ((etot[e] + 127) >> 7);
            kept1[e] = (it < CAP1) ? it : CAP1;
            ovb1[e] = ob; ob += it - kept1[e];
            fb1[e] = fs; fs += CAP1 - kept1[e];
        }
        fb1[NE] = fs;
    }
    __syncthreads();

    for (int i = t; i < NE * CAP1; i += 256) work1[i] = -1;
    __syncthreads();

    int S = Tst[NE];
    for (int idx = t; idx < S * 16; idx += 256) {
        int s = idx >> 4, j = idx & 15;
        int e = 0;
#pragma unroll
        for (int k = 1; k < NE; k++) if (s >= Tst[k]) e = k;
        int sl = s - Tst[e];
        int gr0 = ebase[e] + sl * 128;
        int nv = etot[e] - sl * 128; if (nv > 128) nv = 128;
        int item = (gr0 << 16) | (nv << 8) | (e << 4) | j;
        int q = sl * 16 + j;
        int pos;
        if (q < kept1[e]) pos = e * CAP1 + q;
        else {
            int o = ovb1[e] + (q - kept1[e]);
            int xc = 0;
#pragma unroll
            for (int k = 1; k < NE; k++) if (o >= fb1[k]) xc = k;
            pos = xc * CAP1 + kept1[xc] + (o - fb1[xc]);
        }
        work1[clampi(pos, 0, NE * CAP1 - 1)] = item;
    }

#pragma unroll
    for (int i = 0; i < TPT; i++) {
        int n = t * TPT + i;
        int v = te[i];
#pragma unroll
        for (int k = 0; k < 2; k++) {
            int e = (k ? (v >> 8) : v) & 7;
            int r = clampi(ebase[e] + lpre[t][e]++, 0, NROWS - 1);
            row_tok[r]  = (n << 1) | k;
            row_gate[r] = top_g[2 * n + k];
        }
    }
}

// ---------------- pack x: fp32 [N][D] -> bf16 [N][D] (one-time cast) ----------------
__global__ __launch_bounds__(256) void pack_x_kernel(
    const float* __restrict__ x, unsigned short* __restrict__ xb)
{
    size_t i = (size_t)(blockIdx.x * 256 + threadIdx.x) * 8;
    unsigned short o[8];
    cvt8(x + i, o);
    *(uint4*)(xb + i) = *(uint4*)o;
}

// ---------------- transpose+cast: in[e][K][N] fp32 -> out[e][N][K] bf16 ----------------
__global__ __launch_bounds__(256) void transpose_kernel(
    const float* __restrict__ in, unsigned short* __restrict__ outp, int K, int N)
{
    int e  = blockIdx.z;
    int kb = blockIdx.x;
    int nb = blockIdx.y;
    __shared__ __align__(16) unsigned short tile[64 * LDST];
    int t = threadIdx.x;

    int r = t >> 2, cq = t & 3;
    const float* sp = in + ((size_t)e * K + kb * 64 + r) * N + nb * 64 + cq * 16;
    unsigned short v[16];
    cvt8(sp, v);
    cvt8(sp + 8, v + 8);
    *(uint4*)(&tile[r * LDST + cq * 16 + 0]) = *(uint4*)(v + 0);
    *(uint4*)(&tile[r * LDST + cq * 16 + 8]) = *(uint4*)(v + 8);
    __syncthreads();

    int c = t >> 2, kq = t & 3;
    unsigned short o[16];
#pragma unroll
    for (int i = 0; i < 16; i++) o[i] = tile[(kq * 16 + i) * LDST + c];
    unsigned short* dp = outp + ((size_t)e * N + nb * 64 + c) * K + kb * 64 + kq * 16;
    *(uint4*)(dp + 0) = *(uint4*)(o + 0);
    *(uint4*)(dp + 8) = *(uint4*)(o + 8);
}

// ---------------- FFN1: 128x128 tile, single-buffer, XCD work list, XOR-swizzled LDS ----------------
// Launched TWICE (phase = nb>>3). Per-launch L2 footprint per XCD: xb-slab ~2MB + w1t-half 2MB = 4MB.
__global__ __launch_bounds__(256) void ffn1_fast7(
    const unsigned short* __restrict__ xb,    // [N][D] bf16
    const unsigned short* __restrict__ w1t,   // [e][H][D] bf16
    const float* __restrict__ b1,
    const int* __restrict__ work1,
    const int* __restrict__ row_tok,
    unsigned short* __restrict__ h,
    int phase)
{
    // physical XCD = blockIdx&7; its private work list at [xcd*CAP1, xcd*CAP1+CAP1)
    int lid = blockIdx.x;
    int wv = work1[(lid & 7) * CAP1 + (lid >> 3)];
    if (wv < 0) return;
    int nb     = wv & 15;
    if ((nb >> 3) != phase) return;           // nb-half select
    int e      = (wv >> 4) & 7;
    int nvalid = (wv >> 8) & 0xFF;
    int gr0    = ((unsigned)wv) >> 16;

    __shared__ __align__(16) unsigned short lds[2 * 8192];   // [A|B][128][64] linear, 32 KB
    __shared__ int ltok[128];

    int t = threadIdx.x;
    if (t < 128) {
        int rl = clampi(t, 0, nvalid - 1);
        int idx = clampi(gr0 + rl, 0, NROWS - 1);
        ltok[t] = clampi(row_tok[idx] >> 1, 0, N_TOK - 1);   // decode token
    }
    __syncthreads();

    const int n0 = nb * 128;
    int w = t >> 6;
    const unsigned short* ga[4];
    const unsigned short* gb[4];
    int lofs[4];
#pragma unroll
    for (int i = 0; i < 4; i++) {
        int idx = i * 256 + t;              // 0..1023 -> (row, 16B-chunk)
        int row = idx >> 3, cc = idx & 7;
        int ccs = cc ^ (row & 7);           // pre-swizzled global chunk
        ga[i] = xb + (size_t)ltok[row] * DIM + ccs * 8;
        gb[i] = w1t + ((size_t)e * HID + n0 + row) * DIM + ccs * 8;
        lofs[i] = i * 2048 + w * 512;       // wave-uniform linear LDS dest (shorts)
    }

    int lane = t & 63, quad = lane >> 4, ln = lane & 15;
    int wr = w >> 1, wc = w & 1;
    int xr = ln & 7;                        // read-side XOR key
    f32x4 acc[4][4];
#pragma unroll
    for (int i = 0; i < 4; i++)
#pragma unroll
        for (int j = 0; j < 4; j++) acc[i][j] = (f32x4){0.f, 0.f, 0.f, 0.f};

    for (int kt = 0; kt < DIM / 64; kt++) {
        int k0 = kt * 64;
#pragma unroll
        for (int i = 0; i < 4; i++) {
            gload_lds16(ga[i] + k0, lds + lofs[i]);
            gload_lds16(gb[i] + k0, lds + 8192 + lofs[i]);
        }
        __syncthreads();                     // drains vmcnt(0): tile ready
#pragma unroll
        for (int kk = 0; kk < 2; kk++) {
            bf16x8 af[4], bf[4];
#pragma unroll
            for (int s = 0; s < 4; s++)
                af[s] = *(const bf16x8*)(&lds[(wr * 64 + s * 16 + ln) * 64 + (((kk * 4 + quad) ^ xr) * 8)]);
#pragma unroll
            for (int s = 0; s < 4; s++)
                bf[s] = *(const bf16x8*)(&lds[8192 + (wc * 64 + s * 16 + ln) * 64 + (((kk * 4 + quad) ^ xr) * 8)]);
#pragma unroll
            for (int i = 0; i < 4; i++)
#pragma unroll
                for (int j = 0; j < 4; j++)
                    acc[i][j] = __builtin_amdgcn_mfma_f32_16x16x32_bf16(af[i], bf[j], acc[i][j], 0, 0, 0);
        }
        __syncthreads();                     // reads done before next stage overwrites
    }

    // epilogue: bounce tile through LDS, store coalesced 256B rows
    unsigned short* ob = lds;                // [128][OBST=128] = full 32 KB
#pragma unroll
    for (int j = 0; j < 4; j++) {
        int colL = wc * 64 + j * 16 + ln;
        float bias = b1[e * HID + n0 + colL];
#pragma unroll
        for (int i = 0; i < 4; i++) {
#pragma unroll
            for (int r = 0; r < 4; r++) {
                int m = wr * 64 + i * 16 + quad * 4 + r;
                ob[m * OBST + colL] = f2bf(fast_gelu(acc[i][j][r] + bias));
            }
        }
    }
    __syncthreads();
#pragma unroll
    for (int it = 0; it < 8; it++) {
        int idx = it * 256 + t;              // 0..2047 -> (row, 16B-chunk)
        int m = idx >> 4, ch = idx & 15;
        if (m < nvalid)
            *(uint4*)(h + (size_t)(gr0 + m) * HID + n0 + ch * 8) = *(const uint4*)(ob + m * OBST + ch * 8);
    }
}

// ---------------- FFN2: 128x128 tile, sequential K-half launches, NO atomics ----------------
// j = (kh<<3)|nb. Launch khsel=0: dst = acc*gate (plain store). Launch khsel=1:
// dst += (acc+bias)*gate (single writer per address per launch — stream-ordered).
// Per-launch L2 footprint per XCD: hbuf-half ~2MB + w2t-half 2MB = 4MB.
__global__ __launch_bounds__(256) void ffn2_fast10(
    const unsigned short* __restrict__ h,
    const unsigned short* __restrict__ w2t,   // [e][D][H] bf16
    const float* __restrict__ b2,
    const int* __restrict__ work1,
    const int* __restrict__ row_tok,
    const float* __restrict__ row_gate,
    float* __restrict__ out,                  // k=0 slot
    float* __restrict__ ybuf1,                // k=1 slot
    int khsel)
{
    int lid = blockIdx.x;
    int wv = work1[(lid & 7) * CAP1 + (lid >> 3)];
    if (wv < 0) return;
    int j4     = wv & 15;
    int kh     = j4 >> 3;
    if (kh != khsel) return;                  // K-half select
    int nb     = j4 & 7;
    int e      = (wv >> 4) & 7;
    int nvalid = (wv >> 8) & 0xFF;
    int gr0    = ((unsigned)wv) >> 16;

    __shared__ __align__(16) unsigned short lds[2 * 8192];   // [A|B][128][64] linear, 32 KB
    __shared__ int   ltok2[128];              // (n<<1)|k
    __shared__ float lgate[128];

    int t = threadIdx.x;
    if (t < 128) {
        int rl = clampi(t, 0, nvalid - 1);
        int idx = clampi(gr0 + rl, 0, NROWS - 1);
        ltok2[t] = clampi(row_tok[idx], 0, 2 * N_TOK - 1);
        lgate[t] = row_gate[idx];
    }
    __syncthreads();

    const int n0 = nb * 128;
    const int kbase = kh * (HID / 2);
    int w = t >> 6;
    const unsigned short* ga[4];
    const unsigned short* gb[4];
    int lofs[4];
#pragma unroll
    for (int i = 0; i < 4; i++) {
        int idx = i * 256 + t;
        int row = idx >> 3, cc = idx & 7;
        int ccs = cc ^ (row & 7);           // pre-swizzled global chunk
        int arow = clampi(gr0 + row, 0, NROWS - 1);
        ga[i] = h + (size_t)arow * HID + kbase + ccs * 8;
        gb[i] = w2t + ((size_t)e * DIM + n0 + row) * HID + kbase + ccs * 8;
        lofs[i] = i * 2048 + w * 512;
    }

    int lane = t & 63, quad = lane >> 4, ln = lane & 15;
    int wr = w >> 1, wc = w & 1;
    int xr = ln & 7;
    f32x4 acc[4][4];
#pragma unroll
    for (int i = 0; i < 4; i++)
#pragma unroll
        for (int j = 0; j < 4; j++) acc[i][j] = (f32x4){0.f, 0.f, 0.f, 0.f};

    for (int kt = 0; kt < HID / 2 / 64; kt++) {   // 16 K-steps per half
        int k0 = kt * 64;
#pragma unroll
        for (int i = 0; i < 4; i++) {
            gload_lds16(ga[i] + k0, lds + lofs[i]);
            gload_lds16(gb[i] + k0, lds + 8192 + lofs[i]);
        }
        __syncthreads();
#pragma unroll
        for (int kk = 0; kk < 2; kk++) {
            bf16x8 af[4], bf[4];
#pragma unroll
            for (int s = 0; s < 4; s++)
                af[s] = *(const bf16x8*)(&lds[(wr * 64 + s * 16 + ln) * 64 + (((kk * 4 + quad) ^ xr) * 8)]);
#pragma unroll
            for (int s = 0; s < 4; s++)
                bf[s] = *(const bf16x8*)(&lds[8192 + (wc * 64 + s * 16 + ln) * 64 + (((kk * 4 + quad) ^ xr) * 8)]);
#pragma unroll
            for (int i = 0; i < 4; i++)
#pragma unroll
                for (int j = 0; j < 4; j++)
                    acc[i][j] = __builtin_amdgcn_mfma_f32_16x16x32_bf16(af[i], bf[j], acc[i][j], 0, 0, 0);
        }
        __syncthreads();
    }

#pragma unroll
    for (int j = 0; j < 4; j++) {
        int col = n0 + wc * 64 + j * 16 + ln;
        float bias = (khsel == 1) ? b2[e * DIM + col] : 0.f;
#pragma unroll
        for (int i = 0; i < 4; i++) {
#pragma unroll
            for (int r = 0; r < 4; r++) {
                int m = wr * 64 + i * 16 + quad * 4 + r;
                if (m < nvalid) {
                    int rt  = ltok2[m];
                    int tok = rt >> 1;
                    float vv = (acc[i][j][r] + bias) * lgate[m];
                    float* dst = (rt & 1) ? ybuf1 : out;    // one writer per (tok,col,k) per launch
                    size_t oidx = (size_t)tok * DIM + col;
                    if (khsel == 0) dst[oidx] = vv;
                    else            dst[oidx] += vv;
                }
            }
        }
    }
}

// ---------------- combine: out += ybuf1 ----------------
__global__ __launch_bounds__(256) void combine_kernel(
    float4* __restrict__ out4, const float4* __restrict__ y4)
{
    int i = blockIdx.x * 256 + threadIdx.x;   // 1M float4
    float4 a = out4[i];
    float4 b = y4[i];
    out4[i] = make_float4(a.x + b.x, a.y + b.y, a.z + b.z, a.w + b.w);
}

__global__ __launch_bounds__(256) void zero_out_kernel(float* __restrict__ out) {
    int i = blockIdx.x * 256 + threadIdx.x;
    out[i] = 0.f;
}

// ================= host =================
extern "C" void kernel_launch(void* const* d_in, const int* in_sizes, int n_in,
                              void* d_out, int out_size, void* d_ws, size_t ws_size,
                              hipStream_t stream) {
    const float* x  = (const float*)d_in[0];
    const float* wg = (const float*)d_in[1];
    const float* w1 = (const float*)d_in[2];
    const float* b1 = (const float*)d_in[3];
    const float* w2 = (const float*)d_in[4];
    const float* b2 = (const float*)d_in[5];
    float* out = (float*)d_out;

    // Header (first 128 KB):
    //   [256,8448)      top_e  ushort[4096]
    //   [8448,41216)    top_g  f32[8192]
    //   [41216,73984)   row_tok int[8192]   ((n<<1)|k)
    //   [73984,106752)  row_gate f32[8192]
    //   [106752,111360) work1 int[1152]     ((gr0<<16)|(nvalid<<8)|(e<<4)|j)
    // Data: wt 32M | hbuf 32M | ybuf1 16M  => total 84,017,152 B (unchanged)
    // xb (bf16 x, 8M) ALIASES the first half of ybuf1; ybuf1 is first WRITTEN by
    // ffn2 khsel=0 (after both ffn1 launches read xb) — stream-ordered, safe.
    char* ws = (char*)d_ws;
    unsigned short* top_e    = (unsigned short*)(ws + 256);
    float*          top_g    = (float*)(ws + 8448);
    int*            row_tok  = (int*)(ws + 41216);
    float*          row_gate = (float*)(ws + 73984);
    int*            work1    = (int*)(ws + 106752);

    const size_t WT_OFF    = (size_t)1 << 17;
    const size_t HBUF_OFF  = WT_OFF + (size_t)NE * DIM * HID * 2;      // +32M
    const size_t YBUF_OFF  = HBUF_OFF + (size_t)NROWS * HID * 2;       // +32M
    const size_t NEEDED    = YBUF_OFF + (size_t)N_TOK * DIM * 4;       // +16M = 84,017,152

    if (ws_size < NEEDED) {
        zero_out_kernel<<<dim3(N_TOK * DIM / 256), dim3(256), 0, stream>>>(out);
        return;
    }

    unsigned short* wt    = (unsigned short*)(ws + WT_OFF);
    unsigned short* hbuf  = (unsigned short*)(ws + HBUF_OFF);
    float*          ybuf1 = (float*)(ws + YBUF_OFF);
    unsigned short* xb    = (unsigned short*)(ws + YBUF_OFF);          // alias (see above)

    gate_kernel<<<dim3(N_TOK / 4), dim3(256), 0, stream>>>(x, wg, top_e, top_g);
    scatter_plan_kernel<<<dim3(1), dim3(256), 0, stream>>>(top_e, top_g, row_tok, row_gate, work1);
    pack_x_kernel<<<dim3(N_TOK * DIM / (256 * 8)), dim3(256), 0, stream>>>(x, xb);
    // w1 [e][D][H] -> w1T [e][H][D]
    transpose_kernel<<<dim3(DIM / 64, HID / 64, NE), dim3(256), 0, stream>>>(w1, wt, DIM, HID);
    ffn1_fast7<<<dim3(NE * CAP1), dim3(256), 0, stream>>>(xb, wt, b1, work1, row_tok, hbuf, 0);
    ffn1_fast7<<<dim3(NE * CAP1), dim3(256), 0, stream>>>(xb, wt, b1, work1, row_tok, hbuf, 1);
    // w2 [e][H][D] -> w2T [e][D][H]
    transpose_kernel<<<dim3(HID / 64, DIM / 64, NE), dim3(256), 0, stream>>>(w2, wt, HID, DIM);
    ffn2_fast10<<<dim3(NE * CAP1), dim3(256), 0, stream>>>(hbuf, wt, b2, work1, row_tok, row_gate, out, ybuf1, 0);
    ffn2_fast10<<<dim3(NE * CAP1), dim3(256), 0, stream>>>(hbuf, wt, b2, work1, row_tok, row_gate, out, ybuf1, 1);
    combine_kernel<<<dim3(N_TOK * DIM / 1024), dim3(256), 0, stream>>>((float4*)out, (const float4*)ybuf1);
}

// Round 11
// 360.807 us; speedup vs baseline: 1.2342x; 1.2342x over previous
//
#include <hip/hip_runtime.h>
#include <math.h>
#include <stdint.h>

#define N_TOK 4096
#define DIM   1024
#define HID   2048
#define NE    8
#define NROWS (N_TOK * 2)   // 8192 (token, k) assignments
#define LDST  72            // transpose-kernel LDS tile stride (shorts)
#define OBST  128           // ffn1 epilogue bounce stride (shorts)
#define FBST  132           // ffn2 epilogue bounce stride (floats; 132%32=4 -> quad writes 2-way only)
#define TPT   16            // tokens per thread in scatter_plan (N_TOK/256)
#define CAP1  144           // ffn1 work ranks per XCD (1152/8)
#define CAP2  72            // ffn2 work ranks per XCD (576/8)

typedef __attribute__((ext_vector_type(8))) short bf16x8;
typedef __attribute__((ext_vector_type(4))) float f32x4;

__device__ __forceinline__ unsigned short f2bf(float f) {
    union { unsigned int i; float f; } v; v.f = f;
    unsigned int u = v.i;
    return (unsigned short)((u + 0x7FFFu + ((u >> 16) & 1u)) >> 16);
}
__device__ __forceinline__ int clampi(int v, int lo, int hi) {
    return v < lo ? lo : (v > hi ? hi : v);
}
__device__ __forceinline__ void cvt8(const float* p, unsigned short* o) {
    float4 a = *(const float4*)p;
    float4 b = *(const float4*)(p + 4);
    o[0] = f2bf(a.x); o[1] = f2bf(a.y); o[2] = f2bf(a.z); o[3] = f2bf(a.w);
    o[4] = f2bf(b.x); o[5] = f2bf(b.y); o[6] = f2bf(b.z); o[7] = f2bf(b.w);
}
__device__ __forceinline__ float fast_gelu(float v) {
    float c = 0.7978845608028654f * (v + 0.044715f * v * v * v);
    float t = 1.f - 2.f / (1.f + __expf(2.f * c));   // tanh(c)
    return 0.5f * v * (1.f + t);
}
// async global->LDS, 16B per lane; LDS dest = wave-uniform base + lane*16 (LINEAR — rule #21)
__device__ __forceinline__ void gload_lds16(const void* g, void* l) {
    __builtin_amdgcn_global_load_lds(
        (const __attribute__((address_space(1))) unsigned int*)g,
        (__attribute__((address_space(3))) unsigned int*)l,
        16, 0, 0);
}

// ---------------- gating: one wave per token, pure fp32, NO ATOMICS ----------------
__global__ __launch_bounds__(256) void gate_kernel(
    const float* __restrict__ x, const float* __restrict__ wg,
    unsigned short* __restrict__ top_e, float* __restrict__ top_g)
{
    int wave = threadIdx.x >> 6;
    int lane = threadIdx.x & 63;
    int n = blockIdx.x * 4 + wave;
    if (n >= N_TOK) return;
    float acc[NE];
#pragma unroll
    for (int e = 0; e < NE; e++) acc[e] = 0.f;
    const float* xrow = x + (size_t)n * DIM;
    for (int d = lane; d < DIM; d += 64) {
        float xv = xrow[d];
        float4 wa = *(const float4*)(wg + (size_t)d * NE);
        float4 wb = *(const float4*)(wg + (size_t)d * NE + 4);
        acc[0] += xv * wa.x; acc[1] += xv * wa.y;
        acc[2] += xv * wa.z; acc[3] += xv * wa.w;
        acc[4] += xv * wb.x; acc[5] += xv * wb.y;
        acc[6] += xv * wb.z; acc[7] += xv * wb.w;
    }
#pragma unroll
    for (int e = 0; e < NE; e++) {
        float v = acc[e];
#pragma unroll
        for (int off = 32; off > 0; off >>= 1) v += __shfl_xor(v, off, 64);
        acc[e] = v;
    }
    if (lane == 0) {
        int e0 = 0; float v0 = acc[0];
#pragma unroll
        for (int e = 1; e < NE; e++) if (acc[e] > v0) { v0 = acc[e]; e0 = e; }
        int e1 = (e0 == 0) ? 1 : 0; float v1 = acc[e1];
#pragma unroll
        for (int e = 0; e < NE; e++) if (e != e0 && acc[e] > v1) { v1 = acc[e]; e1 = e; }
        float s = expf(v1 - v0);
        float g0 = 1.f / (1.f + s);
        float g1 = s / (1.f + s);
        top_e[n] = (unsigned short)(e0 | (e1 << 8));
        top_g[2 * n + 0] = g0;
        top_g[2 * n + 1] = g1;
    }
}

// ---------------- scatter+plan: ONE workgroup, zero atomics, PARALLEL work-list build ----------------
__global__ __launch_bounds__(256) void scatter_plan_kernel(
    const unsigned short* __restrict__ top_e, const float* __restrict__ top_g,
    int* __restrict__ row_tok, float* __restrict__ row_gate,
    int* __restrict__ work1, int* __restrict__ work2)
{
    __shared__ int lpre[256][NE];   // counts, then exclusive prefix, then running cursor
    __shared__ int etot[NE], ebase[NE];
    __shared__ int Tst[NE + 1];
    __shared__ int kept1[NE], ovb1[NE], fb1[NE + 1];
    __shared__ int kept2[NE], ovb2[NE], fb2[NE + 1];
    int t = threadIdx.x;

    unsigned long long c64 = 0ull;
    unsigned short te[TPT];
#pragma unroll
    for (int i = 0; i < TPT; i++) {
        int v = top_e[t * TPT + i];
        te[i] = (unsigned short)v;
        c64 += 1ull << ((v & 7) * 8);
        c64 += 1ull << (((v >> 8) & 7) * 8);
    }
#pragma unroll
    for (int e = 0; e < NE; e++) lpre[t][e] = (int)((c64 >> (e * 8)) & 0xFF);
    __syncthreads();

    if (t < NE) {                    // one thread per expert: scan 256 entries
        int s = 0;
        for (int i = 0; i < 256; i++) { int c = lpre[i][t]; lpre[i][t] = s; s += c; }
        etot[t] = s;
    }
    __syncthreads();
    if (t == 0) {
        int b = 0, ts = 0;
#pragma unroll
        for (int e = 0; e < NE; e++) {
            ebase[e] = b; b += etot[e];
            Tst[e] = ts; ts += (etot[e] + 127) >> 7;
        }
        Tst[NE] = ts;
        int ob = 0, fs = 0;
#pragma unroll
        for (int e = 0; e < NE; e++) {
            int it = 16 * ((etot[e] + 127) >> 7);
            kept1[e] = (it < CAP1) ? it : CAP1;
            ovb1[e] = ob; ob += it - kept1[e];
            fb1[e] = fs; fs += CAP1 - kept1[e];
        }
        fb1[NE] = fs;
        ob = 0; fs = 0;
#pragma unroll
        for (int e = 0; e < NE; e++) {
            int it = 8 * ((etot[e] + 127) >> 7);
            kept2[e] = (it < CAP2) ? it : CAP2;
            ovb2[e] = ob; ob += it - kept2[e];
            fb2[e] = fs; fs += CAP2 - kept2[e];
        }
        fb2[NE] = fs;
    }
    __syncthreads();

    for (int i = t; i < NE * CAP1; i += 256) work1[i] = -1;
    for (int i = t; i < NE * CAP2; i += 256) work2[i] = -1;
    __syncthreads();

    int S = Tst[NE];
    for (int idx = t; idx < S * 16; idx += 256) {
        int s = idx >> 4, j = idx & 15;
        int e = 0;
#pragma unroll
        for (int k = 1; k < NE; k++) if (s >= Tst[k]) e = k;
        int sl = s - Tst[e];
        int gr0 = ebase[e] + sl * 128;
        int nv = etot[e] - sl * 128; if (nv > 128) nv = 128;
        int item = (gr0 << 16) | (nv << 8) | (e << 4) | j;
        int q = sl * 16 + j;
        int pos;
        if (q < kept1[e]) pos = e * CAP1 + q;
        else {
            int o = ovb1[e] + (q - kept1[e]);
            int xc = 0;
#pragma unroll
            for (int k = 1; k < NE; k++) if (o >= fb1[k]) xc = k;
            pos = xc * CAP1 + kept1[xc] + (o - fb1[xc]);
        }
        work1[clampi(pos, 0, NE * CAP1 - 1)] = item;
    }
    for (int idx = t; idx < S * 8; idx += 256) {
        int s = idx >> 3, j = idx & 7;
        int e = 0;
#pragma unroll
        for (int k = 1; k < NE; k++) if (s >= Tst[k]) e = k;
        int sl = s - Tst[e];
        int gr0 = ebase[e] + sl * 128;
        int nv = etot[e] - sl * 128; if (nv > 128) nv = 128;
        int item = (gr0 << 16) | (nv << 8) | (e << 4) | j;
        int q = sl * 8 + j;
        int pos;
        if (q < kept2[e]) pos = e * CAP2 + q;
        else {
            int o = ovb2[e] + (q - kept2[e]);
            int xc = 0;
#pragma unroll
            for (int k = 1; k < NE; k++) if (o >= fb2[k]) xc = k;
            pos = xc * CAP2 + kept2[xc] + (o - fb2[xc]);
        }
        work2[clampi(pos, 0, NE * CAP2 - 1)] = item;
    }

#pragma unroll
    for (int i = 0; i < TPT; i++) {
        int n = t * TPT + i;
        int v = te[i];
#pragma unroll
        for (int k = 0; k < 2; k++) {
            int e = (k ? (v >> 8) : v) & 7;
            int r = clampi(ebase[e] + lpre[t][e]++, 0, NROWS - 1);
            row_tok[r]  = (n << 1) | k;
            row_gate[r] = top_g[2 * n + k];
        }
    }
}

// ---------------- pack x: fp32 [N][D] -> bf16 [N][D] (one-time cast) ----------------
__global__ __launch_bounds__(256) void pack_x_kernel(
    const float* __restrict__ x, unsigned short* __restrict__ xb)
{
    size_t i = (size_t)(blockIdx.x * 256 + threadIdx.x) * 8;
    unsigned short o[8];
    cvt8(x + i, o);
    *(uint4*)(xb + i) = *(uint4*)o;
}

// ---------------- transpose+cast: in[e][K][N] fp32 -> out[e][N][K] bf16 ----------------
__global__ __launch_bounds__(256) void transpose_kernel(
    const float* __restrict__ in, unsigned short* __restrict__ outp, int K, int N)
{
    int e  = blockIdx.z;
    int kb = blockIdx.x;
    int nb = blockIdx.y;
    __shared__ __align__(16) unsigned short tile[64 * LDST];
    int t = threadIdx.x;

    int r = t >> 2, cq = t & 3;
    const float* sp = in + ((size_t)e * K + kb * 64 + r) * N + nb * 64 + cq * 16;
    unsigned short v[16];
    cvt8(sp, v);
    cvt8(sp + 8, v + 8);
    *(uint4*)(&tile[r * LDST + cq * 16 + 0]) = *(uint4*)(v + 0);
    *(uint4*)(&tile[r * LDST + cq * 16 + 8]) = *(uint4*)(v + 8);
    __syncthreads();

    int c = t >> 2, kq = t & 3;
    unsigned short o[16];
#pragma unroll
    for (int i = 0; i < 16; i++) o[i] = tile[(kq * 16 + i) * LDST + c];
    unsigned short* dp = outp + ((size_t)e * N + nb * 64 + c) * K + kb * 64 + kq * 16;
    *(uint4*)(dp + 0) = *(uint4*)(o + 0);
    *(uint4*)(dp + 8) = *(uint4*)(o + 8);
}

// ---------------- FFN1: 128x128 tile, single-buffer, XCD work list, XOR-swizzled LDS ----------------
__global__ __launch_bounds__(256) void ffn1_fast6(
    const unsigned short* __restrict__ xb,    // [N][D] bf16
    const unsigned short* __restrict__ w1t,   // [e][H][D] bf16
    const float* __restrict__ b1,
    const int* __restrict__ work1,
    const int* __restrict__ row_tok,
    unsigned short* __restrict__ h)
{
    // physical XCD = blockIdx&7; its private work list at [xcd*CAP1, xcd*CAP1+CAP1)
    int lid = blockIdx.x;
    int wv = work1[(lid & 7) * CAP1 + (lid >> 3)];
    if (wv < 0) return;
    int nb     = wv & 15;
    int e      = (wv >> 4) & 7;
    int nvalid = (wv >> 8) & 0xFF;
    int gr0    = ((unsigned)wv) >> 16;

    __shared__ __align__(16) unsigned short lds[2 * 8192];   // [A|B][128][64] linear, 32 KB
    __shared__ int ltok[128];

    int t = threadIdx.x;
    if (t < 128) {
        int rl = clampi(t, 0, nvalid - 1);
        int idx = clampi(gr0 + rl, 0, NROWS - 1);
        ltok[t] = clampi(row_tok[idx] >> 1, 0, N_TOK - 1);   // decode token
    }
    __syncthreads();

    const int n0 = nb * 128;
    int w = t >> 6;
    const unsigned short* ga[4];
    const unsigned short* gb[4];
    int lofs[4];
#pragma unroll
    for (int i = 0; i < 4; i++) {
        int idx = i * 256 + t;              // 0..1023 -> (row, 16B-chunk)
        int row = idx >> 3, cc = idx & 7;
        int ccs = cc ^ (row & 7);           // pre-swizzled global chunk
        ga[i] = xb + (size_t)ltok[row] * DIM + ccs * 8;
        gb[i] = w1t + ((size_t)e * HID + n0 + row) * DIM + ccs * 8;
        lofs[i] = i * 2048 + w * 512;       // wave-uniform linear LDS dest (shorts)
    }

    int lane = t & 63, quad = lane >> 4, ln = lane & 15;
    int wr = w >> 1, wc = w & 1;
    int xr = ln & 7;                        // read-side XOR key
    f32x4 acc[4][4];
#pragma unroll
    for (int i = 0; i < 4; i++)
#pragma unroll
        for (int j = 0; j < 4; j++) acc[i][j] = (f32x4){0.f, 0.f, 0.f, 0.f};

    for (int kt = 0; kt < DIM / 64; kt++) {
        int k0 = kt * 64;
#pragma unroll
        for (int i = 0; i < 4; i++) {
            gload_lds16(ga[i] + k0, lds + lofs[i]);
            gload_lds16(gb[i] + k0, lds + 8192 + lofs[i]);
        }
        __syncthreads();                     // drains vmcnt(0): tile ready
#pragma unroll
        for (int kk = 0; kk < 2; kk++) {
            bf16x8 af[4], bf[4];
#pragma unroll
            for (int s = 0; s < 4; s++)
                af[s] = *(const bf16x8*)(&lds[(wr * 64 + s * 16 + ln) * 64 + (((kk * 4 + quad) ^ xr) * 8)]);
#pragma unroll
            for (int s = 0; s < 4; s++)
                bf[s] = *(const bf16x8*)(&lds[8192 + (wc * 64 + s * 16 + ln) * 64 + (((kk * 4 + quad) ^ xr) * 8)]);
#pragma unroll
            for (int i = 0; i < 4; i++)
#pragma unroll
                for (int j = 0; j < 4; j++)
                    acc[i][j] = __builtin_amdgcn_mfma_f32_16x16x32_bf16(af[i], bf[j], acc[i][j], 0, 0, 0);
        }
        __syncthreads();                     // reads done before next stage overwrites
    }

    // epilogue: bounce tile through LDS, store coalesced 256B rows
    unsigned short* ob = lds;                // [128][OBST=128] = full 32 KB
#pragma unroll
    for (int j = 0; j < 4; j++) {
        int colL = wc * 64 + j * 16 + ln;
        float bias = b1[e * HID + n0 + colL];
#pragma unroll
        for (int i = 0; i < 4; i++) {
#pragma unroll
            for (int r = 0; r < 4; r++) {
                int m = wr * 64 + i * 16 + quad * 4 + r;
                ob[m * OBST + colL] = f2bf(fast_gelu(acc[i][j][r] + bias));
            }
        }
    }
    __syncthreads();
#pragma unroll
    for (int it = 0; it < 8; it++) {
        int idx = it * 256 + t;              // 0..2047 -> (row, 16B-chunk)
        int m = idx >> 4, ch = idx & 15;
        if (m < nvalid)
            *(uint4*)(h + (size_t)(gr0 + m) * HID + n0 + ch * 8) = *(const uint4*)(ob + m * OBST + ch * 8);
    }
}

// ---------------- FFN2: 128x128 tile, full K, LDS-BOUNCE epilogue (512B/row bursts) ----------------
// The f32 bounce tile [128][FBST] (67.6 KB) is UNION'd with the 32 KB staging buffer.
// Rows stay token-scattered (inherent) but each is ONE 512B burst of float4 stores
// instead of 8 temporally-separated 64B fragments — kills the store-issue/partial-line cost.
__global__ __launch_bounds__(256) void ffn2_fast11(
    const unsigned short* __restrict__ h,
    const unsigned short* __restrict__ w2t,   // [e][D][H] bf16
    const float* __restrict__ b2,
    const int* __restrict__ work2,
    const int* __restrict__ row_tok,
    const float* __restrict__ row_gate,
    float* __restrict__ out,                  // k=0 slot
    float* __restrict__ ybuf1)                // k=1 slot
{
    int lid = blockIdx.x;
    int wv = work2[(lid & 7) * CAP2 + (lid >> 3)];
    if (wv < 0) return;
    int nb     = wv & 15;
    int e      = (wv >> 4) & 7;
    int nvalid = (wv >> 8) & 0xFF;
    int gr0    = ((unsigned)wv) >> 16;

    __shared__ __align__(16) unsigned int smem[128 * FBST]; // 67.6 KB: staging (first 32KB as ushort) / f32 bounce
    __shared__ int   ltok2[128];              // (n<<1)|k
    __shared__ float lgate[128];
    unsigned short* st = (unsigned short*)smem;
    float*          fb = (float*)smem;

    int t = threadIdx.x;
    if (t < 128) {
        int rl = clampi(t, 0, nvalid - 1);
        int idx = clampi(gr0 + rl, 0, NROWS - 1);
        ltok2[t] = clampi(row_tok[idx], 0, 2 * N_TOK - 1);
        lgate[t] = row_gate[idx];
    }
    __syncthreads();

    const int n0 = nb * 128;
    int w = t >> 6;
    const unsigned short* ga[4];
    const unsigned short* gb[4];
    int lofs[4];
#pragma unroll
    for (int i = 0; i < 4; i++) {
        int idx = i * 256 + t;
        int row = idx >> 3, cc = idx & 7;
        int ccs = cc ^ (row & 7);           // pre-swizzled global chunk
        int arow = clampi(gr0 + row, 0, NROWS - 1);
        ga[i] = h + (size_t)arow * HID + ccs * 8;
        gb[i] = w2t + ((size_t)e * DIM + n0 + row) * HID + ccs * 8;
        lofs[i] = i * 2048 + w * 512;
    }

    int lane = t & 63, quad = lane >> 4, ln = lane & 15;
    int wr = w >> 1, wc = w & 1;
    int xr = ln & 7;
    f32x4 acc[4][4];
#pragma unroll
    for (int i = 0; i < 4; i++)
#pragma unroll
        for (int j = 0; j < 4; j++) acc[i][j] = (f32x4){0.f, 0.f, 0.f, 0.f};

    for (int kt = 0; kt < HID / 64; kt++) {
        int k0 = kt * 64;
#pragma unroll
        for (int i = 0; i < 4; i++) {
            gload_lds16(ga[i] + k0, st + lofs[i]);
            gload_lds16(gb[i] + k0, st + 8192 + lofs[i]);
        }
        __syncthreads();
#pragma unroll
        for (int kk = 0; kk < 2; kk++) {
            bf16x8 af[4], bf[4];
#pragma unroll
            for (int s = 0; s < 4; s++)
                af[s] = *(const bf16x8*)(&st[(wr * 64 + s * 16 + ln) * 64 + (((kk * 4 + quad) ^ xr) * 8)]);
#pragma unroll
            for (int s = 0; s < 4; s++)
                bf[s] = *(const bf16x8*)(&st[8192 + (wc * 64 + s * 16 + ln) * 64 + (((kk * 4 + quad) ^ xr) * 8)]);
#pragma unroll
            for (int i = 0; i < 4; i++)
#pragma unroll
                for (int j = 0; j < 4; j++)
                    acc[i][j] = __builtin_amdgcn_mfma_f32_16x16x32_bf16(af[i], bf[j], acc[i][j], 0, 0, 0);
        }
        __syncthreads();                    // last compute reads done -> safe to reuse smem as bounce
    }

    // epilogue phase 1: gated+biased tile -> f32 bounce [128][FBST]
#pragma unroll
    for (int j = 0; j < 4; j++) {
        int colL = wc * 64 + j * 16 + ln;
        float bias = b2[e * DIM + n0 + colL];
#pragma unroll
        for (int i = 0; i < 4; i++) {
#pragma unroll
            for (int r = 0; r < 4; r++) {
                int m = wr * 64 + i * 16 + quad * 4 + r;
                fb[m * FBST + colL] = (acc[i][j][r] + bias) * lgate[m];
            }
        }
    }
    __syncthreads();
    // epilogue phase 2: one 512B float4 burst per row to its token slot
#pragma unroll
    for (int it = 0; it < 16; it++) {
        int idx = it * 256 + t;              // 0..4095 -> (row, 16B-chunk of 32)
        int m = idx >> 5, ch = idx & 31;
        if (m < nvalid) {
            int rt  = ltok2[m];
            int tok = rt >> 1;
            float* dst = (rt & 1) ? ybuf1 : out;   // exactly one writer per (tok,col,k)
            *(float4*)(dst + (size_t)tok * DIM + n0 + ch * 4) = *(const float4*)(fb + m * FBST + ch * 4);
        }
    }
}

// ---------------- combine: out += ybuf1 ----------------
__global__ __launch_bounds__(256) void combine_kernel(
    float4* __restrict__ out4, const float4* __restrict__ y4)
{
    int i = blockIdx.x * 256 + threadIdx.x;   // 1M float4
    float4 a = out4[i];
    float4 b = y4[i];
    out4[i] = make_float4(a.x + b.x, a.y + b.y, a.z + b.z, a.w + b.w);
}

__global__ __launch_bounds__(256) void zero_out_kernel(float* __restrict__ out) {
    int i = blockIdx.x * 256 + threadIdx.x;
    out[i] = 0.f;
}

// ================= host =================
extern "C" void kernel_launch(void* const* d_in, const int* in_sizes, int n_in,
                              void* d_out, int out_size, void* d_ws, size_t ws_size,
                              hipStream_t stream) {
    const float* x  = (const float*)d_in[0];
    const float* wg = (const float*)d_in[1];
    const float* w1 = (const float*)d_in[2];
    const float* b1 = (const float*)d_in[3];
    const float* w2 = (const float*)d_in[4];
    const float* b2 = (const float*)d_in[5];
    float* out = (float*)d_out;

    // Header (first 128 KB):
    //   [256,8448)      top_e  ushort[4096]
    //   [8448,41216)    top_g  f32[8192]
    //   [41216,73984)   row_tok int[8192]   ((n<<1)|k)
    //   [73984,106752)  row_gate f32[8192]
    //   [106752,111360) work1 int[1152]     ((gr0<<16)|(nvalid<<8)|(e<<4)|nb)
    //   [111360,113664) work2 int[576]
    // Data: wt 32M | hbuf 32M | ybuf1 16M  => total 84,017,152 B (unchanged)
    // xb (bf16 x, 8M) ALIASES the first half of ybuf1; ybuf1 is first WRITTEN by
    // ffn2 (after ffn1 has read xb) — stream-ordered, safe.
    char* ws = (char*)d_ws;
    unsigned short* top_e    = (unsigned short*)(ws + 256);
    float*          top_g    = (float*)(ws + 8448);
    int*            row_tok  = (int*)(ws + 41216);
    float*          row_gate = (float*)(ws + 73984);
    int*            work1    = (int*)(ws + 106752);
    int*            work2    = (int*)(ws + 111360);

    const size_t WT_OFF    = (size_t)1 << 17;
    const size_t HBUF_OFF  = WT_OFF + (size_t)NE * DIM * HID * 2;      // +32M
    const size_t YBUF_OFF  = HBUF_OFF + (size_t)NROWS * HID * 2;       // +32M
    const size_t NEEDED    = YBUF_OFF + (size_t)N_TOK * DIM * 4;       // +16M = 84,017,152

    if (ws_size < NEEDED) {
        zero_out_kernel<<<dim3(N_TOK * DIM / 256), dim3(256), 0, stream>>>(out);
        return;
    }

    unsigned short* wt    = (unsigned short*)(ws + WT_OFF);
    unsigned short* hbuf  = (unsigned short*)(ws + HBUF_OFF);
    float*          ybuf1 = (float*)(ws + YBUF_OFF);
    unsigned short* xb    = (unsigned short*)(ws + YBUF_OFF);          // alias (see above)

    gate_kernel<<<dim3(N_TOK / 4), dim3(256), 0, stream>>>(x, wg, top_e, top_g);
    scatter_plan_kernel<<<dim3(1), dim3(256), 0, stream>>>(top_e, top_g, row_tok, row_gate, work1, work2);
    pack_x_kernel<<<dim3(N_TOK * DIM / (256 * 8)), dim3(256), 0, stream>>>(x, xb);
    // w1 [e][D][H] -> w1T [e][H][D]
    transpose_kernel<<<dim3(DIM / 64, HID / 64, NE), dim3(256), 0, stream>>>(w1, wt, DIM, HID);
    ffn1_fast6<<<dim3(NE * CAP1), dim3(256), 0, stream>>>(xb, wt, b1, work1, row_tok, hbuf);
    // w2 [e][H][D] -> w2T [e][D][H]
    transpose_kernel<<<dim3(HID / 64, DIM / 64, NE), dim3(256), 0, stream>>>(w2, wt, HID, DIM);
    ffn2_fast11<<<dim3(NE * CAP2), dim3(256), 0, stream>>>(hbuf, wt, b2, work2, row_tok, row_gate, out, ybuf1);
    combine_kernel<<<dim3(N_TOK * DIM / 1024), dim3(256), 0, stream>>>((float4*)out, (const float4*)ybuf1);
}